// Round 2
// baseline (423.199 us; speedup 1.0000x reference)
//
#include <hip/hip_runtime.h>
#include <hip/hip_bf16.h>
#include <math.h>

#define NB 4
#define NS 2048
#define NE 768
#define NH 12
#define ND 64
#define NQKV 2304
#define BHN (NB*NH)

typedef __attribute__((ext_vector_type(8))) short bf16x8;
typedef __attribute__((ext_vector_type(4))) float f32x4;

__device__ __forceinline__ ushort f2bf(float x){
  __hip_bfloat16 h = __float2bfloat16(x);
  return *reinterpret_cast<ushort*>(&h);
}
__device__ __forceinline__ float bf2f(ushort u){
  __hip_bfloat16 h = *reinterpret_cast<__hip_bfloat16*>(&u);
  return __bfloat162float(h);
}
__device__ __forceinline__ void split2(float x, ushort &hi, ushort &lo){
  ushort h = f2bf(x);
  hi = h;
  lo = f2bf(x - bf2f(h));
}

// ---------------------------------------------------------------------------
// X (fp32) -> Xhi, Xlo (bf16), same layout. 8 elems/thread.
// ---------------------------------------------------------------------------
__global__ __launch_bounds__(256)
void k_convert_x(const float* __restrict__ X, ushort* __restrict__ H, ushort* __restrict__ L)
{
  const int idx = (blockIdx.x*256 + threadIdx.x)*8;
  float4 x0 = *(const float4*)(X+idx);
  float4 x1 = *(const float4*)(X+idx+4);
  float xs[8] = {x0.x,x0.y,x0.z,x0.w,x1.x,x1.y,x1.z,x1.w};
  bf16x8 vh, vl;
#pragma unroll
  for (int i=0;i<8;++i){
    ushort hi, lo; split2(xs[i], hi, lo);
    vh[i] = (short)hi; vl[i] = (short)lo;
  }
  *(bf16x8*)(H+idx) = vh;
  *(bf16x8*)(L+idx) = vl;
}

// ---------------------------------------------------------------------------
// W (fp32, K x N row-major) -> Wt hi/lo (bf16, N x K row-major). 64x64 tiles.
// ---------------------------------------------------------------------------
__global__ __launch_bounds__(256)
void k_transpose_w(const float* __restrict__ W, ushort* __restrict__ TH, ushort* __restrict__ TL,
                   int K, int N)
{
  __shared__ ushort LH[64][72], LL[64][72];
  const int tid = threadIdx.x;
  const int k0 = blockIdx.y*64, n0 = blockIdx.x*64;
  const int kk = tid >> 4, nn = (tid & 15)*4;
#pragma unroll
  for (int p=0;p<4;++p){
    const int k = kk + p*16;
    float4 v = *(const float4*)(W + (size_t)(k0+k)*N + n0 + nn);
    float xs[4] = {v.x, v.y, v.z, v.w};
#pragma unroll
    for (int c=0;c<4;++c){
      ushort hi, lo; split2(xs[c], hi, lo);
      LH[nn+c][k] = hi; LL[nn+c][k] = lo;
    }
  }
  __syncthreads();
  const int nr = tid >> 2, ch = (tid & 3)*16;
  bf16x8 h0, h1, l0, l1;
#pragma unroll
  for (int i=0;i<8;++i){
    h0[i] = (short)LH[nr][ch+i];   h1[i] = (short)LH[nr][ch+8+i];
    l0[i] = (short)LL[nr][ch+i];   l1[i] = (short)LL[nr][ch+8+i];
  }
  ushort* dh = TH + (size_t)(n0+nr)*K + k0 + ch;
  ushort* dl = TL + (size_t)(n0+nr)*K + k0 + ch;
  *(bf16x8*)dh = h0; *(bf16x8*)(dh+8) = h1;
  *(bf16x8*)dl = l0; *(bf16x8*)(dl+8) = l1;
}

// ---------------------------------------------------------------------------
// V [bh][s][64] -> VT [bh][64][s]  (bf16)
// ---------------------------------------------------------------------------
__global__ __launch_bounds__(256)
void k_transpose_v(const ushort* __restrict__ V, ushort* __restrict__ VT)
{
  __shared__ ushort L[64][72];
  const int tid = threadIdx.x;
  const int bh = blockIdx.y;
  const int s0 = blockIdx.x*64;
  const int r = tid >> 2, c = (tid & 3)*16;
  const ushort* src = V + ((size_t)bh*NS + s0 + r)*ND + c;
  *(bf16x8*)&L[r][c]   = *(const bf16x8*)src;
  *(bf16x8*)&L[r][c+8] = *(const bf16x8*)(src+8);
  __syncthreads();
  bf16x8 t0, t1;
#pragma unroll
  for (int i=0;i<8;++i){
    t0[i] = (short)L[c+i][r];
    t1[i] = (short)L[c+8+i][r];
  }
  ushort* dst = VT + ((size_t)bh*ND + r)*NS + s0 + c;
  *(bf16x8*)dst = t0; *(bf16x8*)(dst+8) = t1;
}

// ---------------------------------------------------------------------------
// Split-bf16 emulated-fp32 GEMM via MFMA.
// A: (Ah,Al) M x K bf16 row-major. B: (Bh,Bl) N x K bf16 row-major (= W^T).
// C = Ah*Bh + Ah*Bl + Al*Bh  (fp32 accum).
// 128x128 tile, BK=32, 4 waves, 16x16x32 MFMA, 4x4 frags per wave.
// MODE 0: scatter epilogue to Q/K/V bf16 [bh][s][64].  MODE 1: fp32 C row-major.
// ---------------------------------------------------------------------------
template<int MODE>
__global__ __launch_bounds__(256)
void k_gemm(const ushort* __restrict__ Ah, const ushort* __restrict__ Al,
            const ushort* __restrict__ Bh, const ushort* __restrict__ Bl,
            float* __restrict__ C,
            ushort* __restrict__ Qo, ushort* __restrict__ Ko, ushort* __restrict__ Vo,
            int M, int N, int K)
{
  __shared__ ushort Ash[128][40], Asl[128][40], Bsh[128][40], Bsl[128][40];
  const int tid = threadIdx.x;
  const int lane = tid & 63;
  const int w = tid >> 6;
  const int wm = w & 1, wn = w >> 1;
  const int l15 = lane & 15, lg = lane >> 4;
  const int m0 = blockIdx.y*128, n0 = blockIdx.x*128;

  f32x4 acc[4][4] = {};

  const int sr  = tid >> 1;       // 0..127 tile row
  const int scc = (tid & 1)*16;   // 0/16 k-offset

  for (int k0 = 0; k0 < K; k0 += 32) {
    if (k0) __syncthreads();
    {
      const size_t ao = (size_t)(m0+sr)*K + k0 + scc;
      bf16x8 ah0 = *(const bf16x8*)(Ah+ao), ah1 = *(const bf16x8*)(Ah+ao+8);
      bf16x8 al0 = *(const bf16x8*)(Al+ao), al1 = *(const bf16x8*)(Al+ao+8);
      const size_t bo = (size_t)(n0+sr)*K + k0 + scc;
      bf16x8 bh0 = *(const bf16x8*)(Bh+bo), bh1 = *(const bf16x8*)(Bh+bo+8);
      bf16x8 bl0 = *(const bf16x8*)(Bl+bo), bl1 = *(const bf16x8*)(Bl+bo+8);
      *(bf16x8*)&Ash[sr][scc] = ah0; *(bf16x8*)&Ash[sr][scc+8] = ah1;
      *(bf16x8*)&Asl[sr][scc] = al0; *(bf16x8*)&Asl[sr][scc+8] = al1;
      *(bf16x8*)&Bsh[sr][scc] = bh0; *(bf16x8*)&Bsh[sr][scc+8] = bh1;
      *(bf16x8*)&Bsl[sr][scc] = bl0; *(bf16x8*)&Bsl[sr][scc+8] = bl1;
    }
    __syncthreads();

    bf16x8 fah[4], fal[4], fbh[4], fbl[4];
#pragma unroll
    for (int i=0;i<4;++i){
      fah[i] = *(const bf16x8*)&Ash[wm*64 + i*16 + l15][lg*8];
      fal[i] = *(const bf16x8*)&Asl[wm*64 + i*16 + l15][lg*8];
      fbh[i] = *(const bf16x8*)&Bsh[wn*64 + i*16 + l15][lg*8];
      fbl[i] = *(const bf16x8*)&Bsl[wn*64 + i*16 + l15][lg*8];
    }
#pragma unroll
    for (int mi=0;mi<4;++mi){
#pragma unroll
      for (int ni=0;ni<4;++ni){
        acc[mi][ni] = __builtin_amdgcn_mfma_f32_16x16x32_bf16(fah[mi], fbh[ni], acc[mi][ni], 0,0,0);
        acc[mi][ni] = __builtin_amdgcn_mfma_f32_16x16x32_bf16(fah[mi], fbl[ni], acc[mi][ni], 0,0,0);
        acc[mi][ni] = __builtin_amdgcn_mfma_f32_16x16x32_bf16(fal[mi], fbh[ni], acc[mi][ni], 0,0,0);
      }
    }
  }

#pragma unroll
  for (int mi=0;mi<4;++mi){
#pragma unroll
    for (int ni=0;ni<4;++ni){
#pragma unroll
      for (int j=0;j<4;++j){
        const int m = m0 + wm*64 + mi*16 + lg*4 + j;
        const int n = n0 + wn*64 + ni*16 + l15;
        const float v = acc[mi][ni][j];
        if (MODE == 0) {
          const int bb = m >> 11, ss = m & 2047;
          const int hh = n / 192, rr = n - hh*192;
          ushort* dst = (rr < 64) ? Qo : ((rr < 128) ? Ko : Vo);
          dst[((size_t)(bb*NH + hh)*NS + ss)*ND + (rr & 63)] = f2bf(v);
        } else {
          C[(size_t)m*N + n] = v;
        }
      }
    }
  }
}

// ---------------------------------------------------------------------------
// Flash attention, bf16 MFMA. Block = (qtile 64 rows, h, b), 4 waves.
// Wave w: q rows w*16..w*16+16. Online softmax per q-row.
// Output: attn_out split hi/lo bf16 at [b*S+s][h*64+d] (row-major B*S x 768).
// ---------------------------------------------------------------------------
__global__ __launch_bounds__(256)
void k_attn(const ushort* __restrict__ Qb, const ushort* __restrict__ Kb,
            const ushort* __restrict__ VTb, const int* __restrict__ mask,
            ushort* __restrict__ Ohi, ushort* __restrict__ Olo)
{
  __shared__ ushort Qs[64][72], Ks[64][72], Vs[64][72], Ps[64][72];
  __shared__ float madds[64];

  const int tid = threadIdx.x;
  const int lane = tid & 63;
  const int w = tid >> 6;
  const int l15 = lane & 15, lg = lane >> 4;
  const int qt = blockIdx.x, h = blockIdx.y, b = blockIdx.z;
  const int bh = b*NH + h;

  {
    const int r = tid >> 2, c = (tid & 3)*16;
    const ushort* src = Qb + ((size_t)bh*NS + qt*64 + r)*ND + c;
    *(bf16x8*)&Qs[r][c]   = *(const bf16x8*)src;
    *(bf16x8*)&Qs[r][c+8] = *(const bf16x8*)(src+8);
  }

  float m_run[4], l_run[4];
  f32x4 acc_o[4] = {};
#pragma unroll
  for (int j=0;j<4;++j){ m_run[j] = -INFINITY; l_run[j] = 0.f; }

  for (int kt = 0; kt < NS/64; ++kt) {
    __syncthreads();
    {
      const int r = tid >> 2, c = (tid & 3)*16;
      const ushort* ks = Kb + ((size_t)bh*NS + kt*64 + r)*ND + c;
      *(bf16x8*)&Ks[r][c]   = *(const bf16x8*)ks;
      *(bf16x8*)&Ks[r][c+8] = *(const bf16x8*)(ks+8);
      const ushort* vs = VTb + ((size_t)bh*ND + r)*NS + kt*64 + c;
      *(bf16x8*)&Vs[r][c]   = *(const bf16x8*)vs;
      *(bf16x8*)&Vs[r][c+8] = *(const bf16x8*)(vs+8);
      if (tid < 64) madds[tid] = (mask[b*NS + kt*64 + tid] == 0) ? -INFINITY : 0.f;
    }
    __syncthreads();

    // S = Q K^T  (A = Q rows, B = K rows as K^T)
    bf16x8 aq0 = *(const bf16x8*)&Qs[w*16 + l15][lg*8];
    bf16x8 aq1 = *(const bf16x8*)&Qs[w*16 + l15][32 + lg*8];
    f32x4 s[4];
#pragma unroll
    for (int ni=0; ni<4; ++ni){
      f32x4 z = {};
      bf16x8 kb0 = *(const bf16x8*)&Ks[ni*16 + l15][lg*8];
      bf16x8 kb1 = *(const bf16x8*)&Ks[ni*16 + l15][32 + lg*8];
      z = __builtin_amdgcn_mfma_f32_16x16x32_bf16(aq0, kb0, z, 0,0,0);
      z = __builtin_amdgcn_mfma_f32_16x16x32_bf16(aq1, kb1, z, 0,0,0);
      s[ni] = z;
    }
#pragma unroll
    for (int ni=0; ni<4; ++ni){
      const float ma = madds[ni*16 + l15];
#pragma unroll
      for (int j=0;j<4;++j) s[ni][j] = s[ni][j]*0.125f + ma;
    }

    float tmax[4];
#pragma unroll
    for (int j=0;j<4;++j)
      tmax[j] = fmaxf(fmaxf(s[0][j], s[1][j]), fmaxf(s[2][j], s[3][j]));
#pragma unroll
    for (int j=0;j<4;++j){
#pragma unroll
      for (int d=1; d<16; d<<=1) tmax[j] = fmaxf(tmax[j], __shfl_xor(tmax[j], d));
    }

    float alpha[4], psum[4];
#pragma unroll
    for (int j=0;j<4;++j){
      const float mnew  = fmaxf(m_run[j], tmax[j]);
      const float msafe = fmaxf(mnew, -1e30f);
      alpha[j] = __expf(m_run[j] - msafe);
      m_run[j] = mnew;
      psum[j] = 0.f;
#pragma unroll
      for (int ni=0; ni<4; ++ni){
        const float p = __expf(s[ni][j] - msafe);
        s[ni][j] = p;
        psum[j] += p;
      }
    }
#pragma unroll
    for (int j=0;j<4;++j){
#pragma unroll
      for (int d=1; d<16; d<<=1) psum[j] += __shfl_xor(psum[j], d);
      l_run[j] = l_run[j]*alpha[j] + psum[j];
    }

    // rescale O and write P (bf16) into LDS
#pragma unroll
    for (int ni=0; ni<4; ++ni){
#pragma unroll
      for (int j=0;j<4;++j){
        acc_o[ni][j] *= alpha[j];
        Ps[w*16 + lg*4 + j][ni*16 + l15] = f2bf(s[ni][j]);
      }
    }
    asm volatile("s_waitcnt lgkmcnt(0)" ::: "memory");
    __builtin_amdgcn_sched_barrier(0);

    // O += P V   (A = P rows, B = V^T rows)
    bf16x8 pa0 = *(const bf16x8*)&Ps[w*16 + l15][lg*8];
    bf16x8 pa1 = *(const bf16x8*)&Ps[w*16 + l15][32 + lg*8];
#pragma unroll
    for (int ni=0; ni<4; ++ni){
      bf16x8 vb0 = *(const bf16x8*)&Vs[ni*16 + l15][lg*8];
      bf16x8 vb1 = *(const bf16x8*)&Vs[ni*16 + l15][32 + lg*8];
      acc_o[ni] = __builtin_amdgcn_mfma_f32_16x16x32_bf16(pa0, vb0, acc_o[ni], 0,0,0);
      acc_o[ni] = __builtin_amdgcn_mfma_f32_16x16x32_bf16(pa1, vb1, acc_o[ni], 0,0,0);
    }
  }

  float inv[4];
#pragma unroll
  for (int j=0;j<4;++j) inv[j] = 1.f / l_run[j];
#pragma unroll
  for (int ni=0; ni<4; ++ni){
#pragma unroll
    for (int j=0;j<4;++j){
      const float o = acc_o[ni][j]*inv[j];
      ushort hi, lo; split2(o, hi, lo);
      const size_t row = (size_t)b*NS + qt*64 + w*16 + lg*4 + j;
      const int col = h*ND + ni*16 + l15;
      Ohi[row*NE + col] = hi;
      Olo[row*NE + col] = lo;
    }
  }
}

// ---------------------------------------------------------------------------
extern "C" void kernel_launch(void* const* d_in, const int* in_sizes, int n_in,
                              void* d_out, int out_size, void* d_ws, size_t ws_size,
                              hipStream_t stream)
{
  const float* X    = (const float*)d_in[0];
  const int*   mask = (const int*)d_in[1];
  const float* Wqkv = (const float*)d_in[2];
  const float* Wfc  = (const float*)d_in[3];
  float* out = (float*)d_out;

  char* p = (char*)d_ws;
  const size_t szXE = (size_t)NB*NS*NE;   // 6,291,456
  const size_t szT  = (size_t)BHN*NS*ND;  // 6,291,456
  ushort* Xhi = (ushort*)p; p += szXE*2;
  ushort* Xlo = (ushort*)p; p += szXE*2;
  ushort* Wqh = (ushort*)p; p += (size_t)NQKV*NE*2;
  ushort* Wql = (ushort*)p; p += (size_t)NQKV*NE*2;
  ushort* Wfh = (ushort*)p; p += (size_t)NE*NE*2;
  ushort* Wfl = (ushort*)p; p += (size_t)NE*NE*2;
  ushort* Qb  = (ushort*)p; p += szT*2;
  ushort* Kb  = (ushort*)p; p += szT*2;
  ushort* Vb  = (ushort*)p; p += szT*2;
  ushort* VTb = (ushort*)p; p += szT*2;
  ushort* Ohi = (ushort*)p; p += szXE*2;
  ushort* Olo = (ushort*)p; p += szXE*2;
  // total ws use ~110 MB

  k_convert_x<<<(int)(szXE/2048), 256, 0, stream>>>(X, Xhi, Xlo);
  k_transpose_w<<<dim3(NQKV/64, NE/64), 256, 0, stream>>>(Wqkv, Wqh, Wql, NE, NQKV);
  k_transpose_w<<<dim3(NE/64, NE/64), 256, 0, stream>>>(Wfc, Wfh, Wfl, NE, NE);
  k_gemm<0><<<dim3(NQKV/128, (NB*NS)/128), 256, 0, stream>>>(
      Xhi, Xlo, Wqh, Wql, nullptr, Qb, Kb, Vb, NB*NS, NQKV, NE);
  k_transpose_v<<<dim3(NS/64, BHN), 256, 0, stream>>>(Vb, VTb);
  k_attn<<<dim3(NS/64, NH, NB), 256, 0, stream>>>(Qb, Kb, VTb, mask, Ohi, Olo);
  k_gemm<1><<<dim3(NE/128, (NB*NS)/128), 256, 0, stream>>>(
      Ohi, Olo, Wfh, Wfl, out, nullptr, nullptr, nullptr, NB*NS, NE, NE);
}

// Round 6
// 350.951 us; speedup vs baseline: 1.2059x; 1.2059x over previous
//
#include <hip/hip_runtime.h>
#include <hip/hip_bf16.h>
#include <math.h>

#define NB 4
#define NS 2048
#define NE 768
#define NH 12
#define ND 64
#define NQKV 2304
#define BHN (NB*NH)

typedef __attribute__((ext_vector_type(8))) short bf16x8;
typedef __attribute__((ext_vector_type(4))) float f32x4;
typedef __attribute__((ext_vector_type(16))) float f32x16;
typedef unsigned int uint32;

__device__ __forceinline__ ushort f2bf(float x){
  __hip_bfloat16 h = __float2bfloat16(x);
  return *reinterpret_cast<ushort*>(&h);
}
__device__ __forceinline__ float bf2f(ushort u){
  __hip_bfloat16 h = *reinterpret_cast<__hip_bfloat16*>(&u);
  return __bfloat162float(h);
}
__device__ __forceinline__ void split2(float x, ushort &hi, ushort &lo){
  ushort h = f2bf(x);
  hi = h;
  lo = f2bf(x - bf2f(h));
}
__device__ __forceinline__ uint32 cvtpk(float lo, float hi){
  uint32 r;
  asm("v_cvt_pk_bf16_f32 %0, %1, %2" : "=v"(r) : "v"(lo), "v"(hi));
  return r;
}
__device__ __forceinline__ void pl32swap(uint32 &a, uint32 &b){
  asm("v_permlane32_swap_b32 %0, %1" : "+v"(a), "+v"(b));
}
__device__ __forceinline__ void gl_lds16(const void* g, void* l){
  __builtin_amdgcn_global_load_lds(
      (const __attribute__((address_space(1))) unsigned int*)g,
      (__attribute__((address_space(3))) unsigned int*)l, 16, 0, 0);
}
__device__ __forceinline__ f32x16 zero16(){
  f32x16 z;
#pragma unroll
  for (int i=0;i<16;++i) z[i] = 0.f;
  return z;
}

// ---------------------------------------------------------------------------
// X (fp32) -> Xhi, Xlo (bf16), same layout. 8 elems/thread.
// ---------------------------------------------------------------------------
__global__ __launch_bounds__(256)
void k_convert_x(const float* __restrict__ X, ushort* __restrict__ H, ushort* __restrict__ L)
{
  const int idx = (blockIdx.x*256 + threadIdx.x)*8;
  float4 x0 = *(const float4*)(X+idx);
  float4 x1 = *(const float4*)(X+idx+4);
  float xs[8] = {x0.x,x0.y,x0.z,x0.w,x1.x,x1.y,x1.z,x1.w};
  bf16x8 vh, vl;
#pragma unroll
  for (int i=0;i<8;++i){
    ushort hi, lo; split2(xs[i], hi, lo);
    vh[i] = (short)hi; vl[i] = (short)lo;
  }
  *(bf16x8*)(H+idx) = vh;
  *(bf16x8*)(L+idx) = vl;
}

// ---------------------------------------------------------------------------
// W (fp32, K x N row-major) -> Wt hi/lo (bf16, N x K row-major). 64x64 tiles.
// ---------------------------------------------------------------------------
__global__ __launch_bounds__(256)
void k_transpose_w(const float* __restrict__ W, ushort* __restrict__ TH, ushort* __restrict__ TL,
                   int K, int N)
{
  __shared__ ushort LH[64][72], LL[64][72];
  const int tid = threadIdx.x;
  const int k0 = blockIdx.y*64, n0 = blockIdx.x*64;
  const int kk = tid >> 4, nn = (tid & 15)*4;
#pragma unroll
  for (int p=0;p<4;++p){
    const int k = kk + p*16;
    float4 v = *(const float4*)(W + (size_t)(k0+k)*N + n0 + nn);
    float xs[4] = {v.x, v.y, v.z, v.w};
#pragma unroll
    for (int c=0;c<4;++c){
      ushort hi, lo; split2(xs[c], hi, lo);
      LH[nn+c][k] = hi; LL[nn+c][k] = lo;
    }
  }
  __syncthreads();
  const int nr = tid >> 2, ch = (tid & 3)*16;
  bf16x8 h0, h1, l0, l1;
#pragma unroll
  for (int i=0;i<8;++i){
    h0[i] = (short)LH[nr][ch+i];   h1[i] = (short)LH[nr][ch+8+i];
    l0[i] = (short)LL[nr][ch+i];   l1[i] = (short)LL[nr][ch+8+i];
  }
  ushort* dh = TH + (size_t)(n0+nr)*K + k0 + ch;
  ushort* dl = TL + (size_t)(n0+nr)*K + k0 + ch;
  *(bf16x8*)dh = h0; *(bf16x8*)(dh+8) = h1;
  *(bf16x8*)dl = l0; *(bf16x8*)(dl+8) = l1;
}

// ---------------------------------------------------------------------------
// Pack mask bits per (b, kt-tile, half): bit (r + 16*t) = mask[key(r,h,t)]
// key(r,h,t) = (r&3) + 8*(r>>2) + 4*h + 32*t  (matches 32x32 MFMA D rows)
// ---------------------------------------------------------------------------
__global__ __launch_bounds__(256)
void k_maskprep(const int* __restrict__ mask, uint32* __restrict__ MW)
{
  const int tid = threadIdx.x;
  const int b = tid >> 6, kt = (tid >> 1) & 31, h = tid & 1;
  uint32 wv = 0;
#pragma unroll
  for (int t=0;t<2;++t){
#pragma unroll
    for (int r=0;r<16;++r){
      const int key = (r&3) + 8*(r>>2) + 4*h + 32*t;
      if (mask[b*NS + kt*64 + key] != 0) wv |= (1u << (r + 16*t));
    }
  }
  MW[tid] = wv;
}

// ---------------------------------------------------------------------------
// Split-bf16 GEMM via MFMA.  A: (Ah,Al) MxK bf16 row-major. B: (Bh[,Bl]) NxK.
// NT=3: C = Ah*Bh + Ah*Bl + Al*Bh.  NT=2: C = Ah*Bh + Al*Bh (B eff. bf16).
// MODE 0: scatter to Q/K bf16 [bh][s][64] and V^T bf16 [bh][64][s].
// MODE 1: fp32 C row-major.
// ---------------------------------------------------------------------------
template<int MODE, int NT>
__global__ __launch_bounds__(256)
void k_gemm(const ushort* __restrict__ Ah, const ushort* __restrict__ Al,
            const ushort* __restrict__ Bh, const ushort* __restrict__ Bl,
            float* __restrict__ C,
            ushort* __restrict__ Qo, ushort* __restrict__ Ko, ushort* __restrict__ Vo,
            int M, int N, int K)
{
  __shared__ ushort Ash[128][40], Asl[128][40], Bsh[128][40], Bsl[128][40];
  const int tid = threadIdx.x;
  const int lane = tid & 63;
  const int w = tid >> 6;
  const int wm = w & 1, wn = w >> 1;
  const int l15 = lane & 15, lg = lane >> 4;
  const int m0 = blockIdx.y*128, n0 = blockIdx.x*128;

  f32x4 acc[4][4] = {};

  const int sr  = tid >> 1;
  const int scc = (tid & 1)*16;

  for (int k0 = 0; k0 < K; k0 += 32) {
    if (k0) __syncthreads();
    {
      const size_t ao = (size_t)(m0+sr)*K + k0 + scc;
      bf16x8 ah0 = *(const bf16x8*)(Ah+ao), ah1 = *(const bf16x8*)(Ah+ao+8);
      bf16x8 al0 = *(const bf16x8*)(Al+ao), al1 = *(const bf16x8*)(Al+ao+8);
      const size_t bo = (size_t)(n0+sr)*K + k0 + scc;
      bf16x8 bh0 = *(const bf16x8*)(Bh+bo), bh1 = *(const bf16x8*)(Bh+bo+8);
      *(bf16x8*)&Ash[sr][scc] = ah0; *(bf16x8*)&Ash[sr][scc+8] = ah1;
      *(bf16x8*)&Asl[sr][scc] = al0; *(bf16x8*)&Asl[sr][scc+8] = al1;
      *(bf16x8*)&Bsh[sr][scc] = bh0; *(bf16x8*)&Bsh[sr][scc+8] = bh1;
      if (NT == 3) {
        bf16x8 bl0 = *(const bf16x8*)(Bl+bo), bl1 = *(const bf16x8*)(Bl+bo+8);
        *(bf16x8*)&Bsl[sr][scc] = bl0; *(bf16x8*)&Bsl[sr][scc+8] = bl1;
      }
    }
    __syncthreads();

    bf16x8 fah[4], fal[4], fbh[4], fbl[4];
#pragma unroll
    for (int i=0;i<4;++i){
      fah[i] = *(const bf16x8*)&Ash[wm*64 + i*16 + l15][lg*8];
      fal[i] = *(const bf16x8*)&Asl[wm*64 + i*16 + l15][lg*8];
      fbh[i] = *(const bf16x8*)&Bsh[wn*64 + i*16 + l15][lg*8];
      if (NT == 3) fbl[i] = *(const bf16x8*)&Bsl[wn*64 + i*16 + l15][lg*8];
    }
#pragma unroll
    for (int mi=0;mi<4;++mi){
#pragma unroll
      for (int ni=0;ni<4;++ni){
        acc[mi][ni] = __builtin_amdgcn_mfma_f32_16x16x32_bf16(fah[mi], fbh[ni], acc[mi][ni], 0,0,0);
        if (NT == 3)
          acc[mi][ni] = __builtin_amdgcn_mfma_f32_16x16x32_bf16(fah[mi], fbl[ni], acc[mi][ni], 0,0,0);
        acc[mi][ni] = __builtin_amdgcn_mfma_f32_16x16x32_bf16(fal[mi], fbh[ni], acc[mi][ni], 0,0,0);
      }
    }
  }

#pragma unroll
  for (int mi=0;mi<4;++mi){
#pragma unroll
    for (int ni=0;ni<4;++ni){
#pragma unroll
      for (int j=0;j<4;++j){
        const int m = m0 + wm*64 + mi*16 + lg*4 + j;
        const int n = n0 + wn*64 + ni*16 + l15;
        const float v = acc[mi][ni][j];
        if (MODE == 0) {
          const int bb = m >> 11, ss = m & 2047;
          const int hh = n / 192, rr = n - hh*192;
          const int d = rr & 63;
          if (rr < 128) {
            ushort* dst = (rr < 64) ? Qo : Ko;
            dst[((size_t)(bb*NH + hh)*NS + ss)*ND + d] = f2bf(v);
          } else {
            Vo[((size_t)(bb*NH + hh)*ND + d)*NS + ss] = f2bf(v);  // V^T
          }
        } else {
          C[(size_t)m*N + n] = v;
        }
      }
    }
  }
}

// ---------------------------------------------------------------------------
// Flash attention, swapped-QK^T 32x32x16 MFMA.
// Block = 256 thr = 4 waves; wave owns 32 q-rows; block = 128 q-rows.
// Lane (q=lane&31, h=lane>>5). S^T = mfma(K_frag, Q_frag): lane holds 32
// score regs, all for q-row q (keys (r&3)+8*(r>>2)+4h+32t). Softmax in-reg
// + one shfl_xor(32). P fragments built via cvt_pk_bf16 + permlane32_swap.
// K/V^T staged via global_load_lds, XOR-swizzled (pre-swizzled global src).
// ---------------------------------------------------------------------------
__global__ __launch_bounds__(256)
void k_attn(const ushort* __restrict__ Qb, const ushort* __restrict__ Kb,
            const ushort* __restrict__ VTb, const uint32* __restrict__ MW,
            ushort* __restrict__ Ohi, ushort* __restrict__ Olo)
{
  __shared__ ushort Kls[2][4096];  // [buf][64 keys][64 d] swizzled
  __shared__ ushort Vls[2][4096];  // [buf][64 d][64 keys] swizzled

  const int tid = threadIdx.x;
  const int lane = tid & 63;
  const int w = tid >> 6;
  const int l31 = lane & 31;
  const int h = lane >> 5;
  const int qt = blockIdx.x, head = blockIdx.y, b = blockIdx.z;
  const int bh = b*NH + head;
  const int qglob = qt*128 + w*32 + l31;

  // Q B-fragments: lane (q,h), frag s holds Q[q][s*16 + h*8 .. +8]
  bf16x8 qf[4];
  {
    const ushort* qp = Qb + ((size_t)bh*NS + qglob)*ND + h*8;
#pragma unroll
    for (int s=0;s<4;++s) qf[s] = *(const bf16x8*)(qp + s*16);
  }

  // staging geometry: issue i covers rows i*32 + w*8 + lane/8; the global
  // column is pre-swizzled so the linear LDS write lands XOR-swizzled.
  const int srow = (w<<3) + (lane>>3);
  const int scol = ((lane&7) ^ (lane>>3)) << 3;   // in ushorts
  const ushort* Kg  = Kb  + (size_t)bh*NS*ND;
  const ushort* VTg = VTb + (size_t)bh*ND*NS;
  const int lbase = (w<<9);                        // ushorts

#define STAGE(kt_, bsel_)                                                     \
  {                                                                           \
    _Pragma("unroll")                                                         \
    for (int i_=0;i_<2;++i_){                                                 \
      const int row_ = i_*32 + srow;                                          \
      gl_lds16(Kg  + (size_t)((kt_)*64 + row_)*ND + scol,                     \
               &Kls[bsel_][i_*2048 + lbase]);                                 \
      gl_lds16(VTg + (size_t)row_*NS + (kt_)*64 + scol,                       \
               &Vls[bsel_][i_*2048 + lbase]);                                 \
    }                                                                         \
  }

  f32x16 o0 = zero16(), o1 = zero16();
  float m_run = -INFINITY, l_run = 0.f;

  STAGE(0, 0);
  __syncthreads();

  for (int kt = 0; kt < NS/64; ++kt){
    const int buf = kt & 1;
    if (kt + 1 < NS/64) STAGE(kt+1, buf^1);
    const uint32 mw = MW[b*64 + kt*2 + h];

    // S^T = K * Q^T
    f32x16 z0 = zero16(), z1 = zero16();
    const char* kbase = (const char*)&Kls[buf][0];
#pragma unroll
    for (int s=0;s<4;++s){
      const int cb = (s*32 + h*16) ^ ((l31&7)<<4);
      bf16x8 kf0 = *(const bf16x8*)(kbase + l31*128 + cb);
      z0 = __builtin_amdgcn_mfma_f32_32x32x16_bf16(kf0, qf[s], z0, 0,0,0);
      bf16x8 kf1 = *(const bf16x8*)(kbase + (32+l31)*128 + cb);
      z1 = __builtin_amdgcn_mfma_f32_32x32x16_bf16(kf1, qf[s], z1, 0,0,0);
    }

    // online softmax: 32 scores here + 32 in partner lane (lane^32)
    float sc[32];
    float tmax = -INFINITY;
#pragma unroll
    for (int r=0;r<16;++r){
      float s0 = z0[r]*0.125f;
      s0 = (mw & (1u<<r)) ? s0 : -INFINITY;
      sc[r] = s0;
      float s1 = z1[r]*0.125f;
      s1 = (mw & (1u<<(16+r))) ? s1 : -INFINITY;
      sc[16+r] = s1;
      tmax = fmaxf(tmax, fmaxf(s0, s1));
    }
    tmax = fmaxf(tmax, __shfl_xor(tmax, 32));
    const float mnew  = fmaxf(m_run, tmax);
    const float msafe = fmaxf(mnew, -1e30f);
    const float alpha = __expf(m_run - msafe);
    float psum = 0.f;
#pragma unroll
    for (int r=0;r<32;++r){
      float p = __expf(sc[r] - msafe);
      sc[r] = p;
      psum += p;
    }
    psum += __shfl_xor(psum, 32);
    l_run = l_run*alpha + psum;
    m_run = mnew;
#pragma unroll
    for (int r=0;r<16;++r){ o0[r] *= alpha; o1[r] *= alpha; }

    // O^T += V^T * P^T ; P-fragments built in-register
    const char* vbase = (const char*)&Vls[buf][0];
#pragma unroll
    for (int ks=0;ks<4;++ks){
      const int rb = (ks&1)*8 + (ks>>1)*16;
      uint32 d0 = cvtpk(sc[rb+0], sc[rb+1]);
      uint32 d2 = cvtpk(sc[rb+4], sc[rb+5]);
      pl32swap(d0, d2);
      uint32 d1 = cvtpk(sc[rb+2], sc[rb+3]);
      uint32 d3 = cvtpk(sc[rb+6], sc[rb+7]);
      pl32swap(d1, d3);
      union { uint32 u[4]; bf16x8 v; } pf;
      pf.u[0] = d0; pf.u[1] = d1; pf.u[2] = d2; pf.u[3] = d3;
      const int cb = (ks*32 + h*16) ^ ((l31&7)<<4);
      bf16x8 vf0 = *(const bf16x8*)(vbase + l31*128 + cb);
      o0 = __builtin_amdgcn_mfma_f32_32x32x16_bf16(vf0, pf.v, o0, 0,0,0);
      bf16x8 vf1 = *(const bf16x8*)(vbase + (32+l31)*128 + cb);
      o1 = __builtin_amdgcn_mfma_f32_32x32x16_bf16(vf1, pf.v, o1, 0,0,0);
    }
    __syncthreads();
  }

  // epilogue: thread holds O[q][d] for d = (r&3)+8*(r>>2)+4h+32a
  const float inv = 1.f / l_run;
  const size_t obase = ((size_t)(b*NS + qglob))*NE + head*ND;
#pragma unroll
  for (int a=0;a<2;++a){
#pragma unroll
    for (int rp=0;rp<8;++rp){
      const int r = rp*2;
      const float v0 = (a ? o1[r]   : o0[r])   * inv;
      const float v1 = (a ? o1[r+1] : o0[r+1]) * inv;
      ushort h0,lo0,h1,lo1;
      split2(v0, h0, lo0); split2(v1, h1, lo1);
      const int d = (r&3) + 8*(r>>2) + 4*h + 32*a;
      *(uint32*)(Ohi + obase + d) = (uint32)h0 | ((uint32)h1<<16);
      *(uint32*)(Olo + obase + d) = (uint32)lo0 | ((uint32)lo1<<16);
    }
  }
#undef STAGE
}

// ---------------------------------------------------------------------------
extern "C" void kernel_launch(void* const* d_in, const int* in_sizes, int n_in,
                              void* d_out, int out_size, void* d_ws, size_t ws_size,
                              hipStream_t stream)
{
  const float* X    = (const float*)d_in[0];
  const int*   mask = (const int*)d_in[1];
  const float* Wqkv = (const float*)d_in[2];
  const float* Wfc  = (const float*)d_in[3];
  float* out = (float*)d_out;

  char* p = (char*)d_ws;
  const size_t szXE = (size_t)NB*NS*NE;
  const size_t szT  = (size_t)BHN*NS*ND;
  ushort* Xhi = (ushort*)p; p += szXE*2;
  ushort* Xlo = (ushort*)p; p += szXE*2;
  ushort* Wqh = (ushort*)p; p += (size_t)NQKV*NE*2;
  ushort* Wql = (ushort*)p; p += (size_t)NQKV*NE*2;
  ushort* Wfh = (ushort*)p; p += (size_t)NE*NE*2;
  ushort* Wfl = (ushort*)p; p += (size_t)NE*NE*2;
  ushort* Qb  = (ushort*)p; p += szT*2;
  ushort* Kb  = (ushort*)p; p += szT*2;
  ushort* VTb = (ushort*)p; p += szT*2;
  ushort* Ohi = (ushort*)p; p += szXE*2;
  ushort* Olo = (ushort*)p; p += szXE*2;
  uint32* MW  = (uint32*)p; p += 256*4;

  k_convert_x<<<(int)(szXE/2048), 256, 0, stream>>>(X, Xhi, Xlo);
  k_transpose_w<<<dim3(NQKV/64, NE/64), 256, 0, stream>>>(Wqkv, Wqh, Wql, NE, NQKV);
  k_transpose_w<<<dim3(NE/64, NE/64), 256, 0, stream>>>(Wfc, Wfh, Wfl, NE, NE);
  k_maskprep<<<1, 256, 0, stream>>>(mask, MW);
  // QKV projection: 2-term (W_qkv effectively bf16; Q/K/V are bf16 anyway)
  k_gemm<0,2><<<dim3(NQKV/128, (NB*NS)/128), 256, 0, stream>>>(
      Xhi, Xlo, Wqh, Wql, nullptr, Qb, Kb, VTb, NB*NS, NQKV, NE);
  k_attn<<<dim3(NS/128, NH, NB), 256, 0, stream>>>(Qb, Kb, VTb, MW, Ohi, Olo);
  // output projection: full 3-term split (fp32 output precision)
  k_gemm<1,3><<<dim3(NE/128, (NB*NS)/128), 256, 0, stream>>>(
      Ohi, Olo, Wfh, Wfl, out, nullptr, nullptr, nullptr, NB*NS, NE, NE);
}